// Round 1
// baseline (6123.328 us; speedup 1.0000x reference)
//
#include <hip/hip_runtime.h>
#include <stdint.h>

typedef __attribute__((ext_vector_type(8))) short bf16x8;
typedef __attribute__((ext_vector_type(4))) float f32x4;
typedef unsigned short u16;
typedef unsigned int u32;
typedef unsigned long long u64;

#define DEV static __device__ __forceinline__

// Problem constants: B=64, S=256, C=12, Ec=50, Hc=64, Ew=300, Hw=320, Din=428, NT=20
// word count N = B*S = 16384. x rows are r = t*64 + b (time-major == packed order).

DEV u16 f2b(float f){ union{float f; u32 u;} v; v.f=f; return (u16)((v.u + 0x7FFFu + ((v.u>>16)&1u))>>16); }
DEV float b2f(u16 b){ union{u32 u; float f;} v; v.u=((u32)b)<<16; return v.f; }
DEV float sigm(float x){ return 1.0f/(1.0f + __expf(-x)); }
DEV float tanhf2(float x){ float a=fabsf(x); float e=__expf(-2.0f*a); float t=(1.0f-e)/(1.0f+e); return x<0.0f? -t : t; }

// ---------------- flag init ----------------
__global__ void k_init(u32* flags){ flags[threadIdx.x] = 0u; }

// ---------------- char BiLSTM (fused emb-gather + input-proj + recurrence) ----------------
// grid 512: dir = bid&1, 64 words per WG. Combined W = [Wih | Whh | bias] K=115 pad 128.
// gate layout n = col*4 + gtype (i,f,g,o interleaved per column) so each col's 4 gates are LDS-adjacent.
__global__ __launch_bounds__(256,1) void k_char(
    const int* __restrict__ char_ids, const float* __restrict__ cemb,
    const float* __restrict__ h0g, const float* __restrict__ c0g,
    const float* __restrict__ WihF, const float* __restrict__ WhhF,
    const float* __restrict__ bihF, const float* __restrict__ bhhF,
    const float* __restrict__ WihB, const float* __restrict__ WhhB,
    const float* __restrict__ bihB, const float* __restrict__ bhhB,
    u16* __restrict__ cfF, u16* __restrict__ cfB)
{
  __shared__ __align__(16) u16 Wl[256*128];  // swizzled [n][k]
  __shared__ __align__(16) u16 Xc[64*128];   // swizzled [word][k] = [emb(50)|h(64)|1|0pad]
  __shared__ __align__(16) u16 Gc[64*256];   // gates bf16

  const int dir = blockIdx.x & 1;
  const int n0  = (blockIdx.x >> 1) * 64;
  const int tid = threadIdx.x;
  const int lane = tid & 63, wv = tid >> 6;
  const int l15 = lane & 15, l4 = lane >> 4;

  const float* Wih = dir ? WihB : WihF;
  const float* Whh = dir ? WhhB : WhhF;
  const float* bih = dir ? bihB : bihF;
  const float* bhh = dir ? bhhB : bhhF;
  const float* h0 = h0g + dir*64;
  const float* c0 = c0g + dir*64;

  {
    const int n = tid; const int gt = n & 3, col = n >> 2;
    const int grow = gt*64 + col;
    for (int k = 0; k < 128; ++k){
      float v;
      if (k < 50) v = Wih[grow*50 + k];
      else if (k < 114) v = Whh[grow*64 + (k-50)];
      else if (k == 114) v = bih[grow] + bhh[grow];
      else v = 0.0f;
      Wl[n*128 + (k ^ ((n&7)<<3))] = f2b(v);
    }
  }
  for (int idx = tid; idx < 64*128; idx += 256){
    int w = idx >> 7, k = idx & 127;
    float v = (k==114) ? 1.0f : ((k>=50 && k<114) ? h0[k-50] : 0.0f);
    Xc[w*128 + (k ^ ((w&7)<<3))] = f2b(v);
  }
  const int uw = tid >> 2, ucb = (tid & 3) * 16;
  float cst[16], hreg[16];
  #pragma unroll
  for (int cc = 0; cc < 16; ++cc){ cst[cc] = c0[ucb + cc]; hreg[cc] = 0.0f; }

  for (int t = 0; t < 12; ++t){
    const int cpos = dir ? (11 - t) : t;
    __syncthreads();
    for (int idx = tid; idx < 3200; idx += 256){
      int w = idx / 50, k = idx - w*50;
      int cid = char_ids[(n0 + w)*12 + cpos];
      Xc[w*128 + (k ^ ((w&7)<<3))] = f2b(cemb[cid*50 + k]);
    }
    __syncthreads();
    f32x4 acc[4][4];
    #pragma unroll
    for (int mt=0; mt<4; ++mt)
      #pragma unroll
      for (int nt=0; nt<4; ++nt)
        #pragma unroll
        for (int j=0;j<4;++j) acc[mt][nt][j] = 0.0f;
    #pragma unroll
    for (int kk = 0; kk < 4; ++kk){
      bf16x8 A[4];
      #pragma unroll
      for (int mt=0; mt<4; ++mt){
        int row = mt*16 + l15;
        A[mt] = *(const bf16x8*)&Xc[row*128 + ((kk*32 + 8*l4) ^ ((row&7)<<3))];
      }
      #pragma unroll
      for (int nt=0; nt<4; ++nt){
        int n = wv*64 + nt*16 + l15;
        bf16x8 Bf = *(const bf16x8*)&Wl[n*128 + ((kk*32 + 8*l4) ^ ((n&7)<<3))];
        #pragma unroll
        for (int mt=0; mt<4; ++mt)
          acc[mt][nt] = __builtin_amdgcn_mfma_f32_16x16x32_bf16(A[mt], Bf, acc[mt][nt], 0,0,0);
      }
    }
    #pragma unroll
    for (int mt=0; mt<4; ++mt)
      #pragma unroll
      for (int nt=0; nt<4; ++nt)
        #pragma unroll
        for (int j=0;j<4;++j){
          int m = mt*16 + l4*4 + j;
          int n = wv*64 + nt*16 + l15;
          Gc[m*256 + n] = f2b(acc[mt][nt][j]);
        }
    __syncthreads();
    #pragma unroll
    for (int cc=0; cc<16; ++cc){
      int col = ucb + cc;
      const u16* gp = &Gc[uw*256 + col*4];
      float gi=b2f(gp[0]), gf=b2f(gp[1]), gg=b2f(gp[2]), go=b2f(gp[3]);
      float c2 = sigm(gf)*cst[cc] + sigm(gi)*tanhf2(gg);
      cst[cc]=c2;
      float h = sigm(go)*tanhf2(c2);
      hreg[cc]=h;
      Xc[uw*128 + ((50+col) ^ ((uw&7)<<3))] = f2b(h);
    }
  }
  u16* cf = dir ? cfB : cfF;
  #pragma unroll
  for (int cc=0; cc<16; ++cc) cf[(u64)(n0+uw)*64 + ucb + cc] = f2b(hreg[cc]);
}

// ---------------- build x [16384][448] bf16: [we(300)|cf_f(64)|cf_b(64)|1|0..] ----------------
__global__ __launch_bounds__(256,1) void k_buildx(
    const int* __restrict__ sents, const float* __restrict__ wemb,
    const u16* __restrict__ cfF, const u16* __restrict__ cfB,
    u16* __restrict__ xg)
{
  const int r = blockIdx.x*4 + (threadIdx.x >> 6);
  const int lane = threadIdx.x & 63;
  const int t = r >> 6, b = r & 63;
  const int sid = sents[b*256 + t];
  const int n = b*256 + t;                    // char word index (b-major)
  u32* xr = (u32*)(xg + (u64)r*448);
  const float* we = wemb + (u64)sid*300;
  const u16* cf = cfF + (u64)n*64;
  const u16* cb = cfB + (u64)n*64;
  for (int u = lane; u < 224; u += 64){
    int c0 = 2*u, c1 = 2*u + 1;
    u16 lo = (c0 < 300) ? f2b(we[c0]) : (c0 < 364) ? cf[c0-300] : (c0 < 428) ? cb[c0-364] : (c0==428) ? f2b(1.0f) : (u16)0;
    u16 hi = (c1 < 300) ? f2b(we[c1]) : (c1 < 364) ? cf[c1-300] : (c1 < 428) ? cb[c1-364] : (c1==428) ? f2b(1.0f) : (u16)0;
    xr[u] = (u32)lo | ((u32)hi << 16);
  }
}

// ---------------- word BiLSTM: 20 persistent WGs (10 per dir, 32 h-cols each) ----------------
DEV void pre_compute(f32x4 (&ACC)[2][4], int tn,
                     const u16* __restrict__ xg, u16* Xs,
                     const bf16x8 (&BWih)[2][14],
                     int tid, int l15, int l4)
{
  {
    const u16* src = xg + (u64)tn * 64 * 448;
    #pragma unroll
    for (int p = 0; p < 28; ++p){
      int idx = tid + 256*p;
      int row = idx / 112, e = idx - row*112;
      u64 v = *(const u64*)(src + row*448 + e*4);
      *(u64*)&Xs[row*456 + e*4] = v;
    }
  }
  __syncthreads();
  #pragma unroll
  for (int nt=0; nt<2; ++nt)
    #pragma unroll
    for (int mt=0; mt<4; ++mt)
      #pragma unroll
      for (int j=0;j<4;++j) ACC[nt][mt][j] = 0.0f;
  #pragma unroll
  for (int kk = 0; kk < 14; ++kk){
    bf16x8 A[4];
    #pragma unroll
    for (int mt=0; mt<4; ++mt)
      A[mt] = *(const bf16x8*)&Xs[(mt*16 + l15)*456 + kk*32 + 8*l4];
    #pragma unroll
    for (int nt=0; nt<2; ++nt)
      #pragma unroll
      for (int mt=0; mt<4; ++mt)
        ACC[nt][mt] = __builtin_amdgcn_mfma_f32_16x16x32_bf16(A[mt], BWih[nt][kk], ACC[nt][mt], 0,0,0);
  }
}

DEV void word_body(int i, int dir, int wg, int t,
                   f32x4 (&ACCC)[2][4], f32x4 (&ACCN)[2][4],
                   const bf16x8 (&BWih)[2][14], const bf16x8 (&BWhh)[2][10],
                   float (&cst)[8],
                   const u16* __restrict__ xg, u16* __restrict__ h_g,
                   u32* __restrict__ flags, u16* __restrict__ hs,
                   u16* Hs, u16* Xs, float* G,
                   int tid, int l15, int l4, int wv, int ucol, int ub0)
{
  if (i > 0){
    if (tid < 10){
      u32 tgt = (u32)i; int guard = 0;
      while (__hip_atomic_load(&flags[dir*16 + tid], __ATOMIC_ACQUIRE, __HIP_MEMORY_SCOPE_AGENT) < tgt){
        __builtin_amdgcn_s_sleep(4);
        if (++guard > (1<<24)) break;   // safety: never triggers when protocol healthy
      }
    }
    __syncthreads();
    {
      const u64* hb = (const u64*)(h_g + (u64)(((i-1)&1)*2 + dir)*64*320);
      #pragma unroll
      for (int p=0; p<20; ++p){
        int idx = tid + 256*p;
        int row = idx / 80, e = idx - row*80;
        u64 v = __hip_atomic_load(&hb[row*80 + e], __ATOMIC_RELAXED, __HIP_MEMORY_SCOPE_AGENT);
        *(u64*)&Hs[row*328 + e*4] = v;
      }
    }
    __syncthreads();
    #pragma unroll
    for (int kk=0; kk<10; ++kk){
      bf16x8 A[4];
      #pragma unroll
      for (int mt=0; mt<4; ++mt)
        A[mt] = *(const bf16x8*)&Hs[(mt*16 + l15)*328 + kk*32 + 8*l4];
      #pragma unroll
      for (int nt=0; nt<2; ++nt)
        #pragma unroll
        for (int mt=0; mt<4; ++mt)
          ACCC[nt][mt] = __builtin_amdgcn_mfma_f32_16x16x32_bf16(A[mt], BWhh[nt][kk], ACCC[nt][mt], 0,0,0);
    }
  }
  #pragma unroll
  for (int nt=0; nt<2; ++nt)
    #pragma unroll
    for (int mt=0; mt<4; ++mt)
      #pragma unroll
      for (int j=0;j<4;++j)
        G[(mt*16 + l4*4 + j)*128 + wv*32 + nt*16 + l15] = ACCC[nt][mt][j];
  __syncthreads();
  {
    u16* hw = h_g + (u64)((i&1)*2 + dir)*64*320;
    #pragma unroll
    for (int p=0; p<8; ++p){
      int b = ub0 + 8*p;
      const float4 g4 = *(const float4*)&G[b*128 + ucol*4];   // (i,f,g,o)
      float c2 = sigm(g4.y)*cst[p] + sigm(g4.x)*tanhf2(g4.z);
      cst[p] = c2;
      float h = sigm(g4.w)*tanhf2(c2);
      u16 hb16 = f2b(h);
      __hip_atomic_store(&hw[b*320 + wg*32 + ucol], hb16, __ATOMIC_RELAXED, __HIP_MEMORY_SCOPE_AGENT);
      hs[(u64)(t*64 + b)*640 + dir*320 + wg*32 + ucol] = hb16;
    }
  }
  __threadfence();
  __syncthreads();
  if (tid == 0)
    __hip_atomic_store(&flags[dir*16 + wg], (u32)(i+1), __ATOMIC_RELEASE, __HIP_MEMORY_SCOPE_AGENT);
  if (i < 255){
    int tn = dir ? (254 - i) : (i + 1);
    pre_compute(ACCN, tn, xg, Xs, BWih, tid, l15, l4);   // fills the spin slack of other WGs
  }
}

__global__ __launch_bounds__(256,1) void k_word(
    const u16* __restrict__ xg,
    const float* __restrict__ WihFg, const float* __restrict__ WhhFg,
    const float* __restrict__ bihFg, const float* __restrict__ bhhFg,
    const float* __restrict__ WihBg, const float* __restrict__ WhhBg,
    const float* __restrict__ bihBg, const float* __restrict__ bhhBg,
    u16* __restrict__ h_g, u32* __restrict__ flags, u16* __restrict__ hs)
{
  __shared__ __align__(16) u16 Hs[64*328];   // h stage, padded stride
  __shared__ __align__(16) u16 Xs[64*456];   // x slice stage, padded stride
  __shared__ __align__(16) float G[64*128];  // gate redistribute

  const int wgid = blockIdx.x;
  const int dir = wgid / 10;
  const int wg  = wgid - dir*10;
  const int tid = threadIdx.x;
  const int lane = tid & 63, wv = tid >> 6;
  const int l15 = lane & 15, l4 = lane >> 4;
  const int ucol = tid & 31, ub0 = tid >> 5;

  const float* Wih = dir ? WihBg : WihFg;
  const float* Whh = dir ? WhhBg : WhhFg;
  const float* bih = dir ? bihBg : bihFg;
  const float* bhh = dir ? bhhBg : bhhFg;

  // persistent weight fragments in registers. local gate q = col*4 + gtype.
  bf16x8 BWih[2][14];
  bf16x8 BWhh[2][10];
  #pragma unroll
  for (int nt=0; nt<2; ++nt){
    const int q = wv*32 + nt*16 + l15;
    const int col = q >> 2, gt = q & 3;
    const int grow = gt*320 + wg*32 + col;
    #pragma unroll
    for (int kk=0; kk<14; ++kk){
      bf16x8 v;
      #pragma unroll
      for (int j=0;j<8;++j){
        int k = kk*32 + 8*l4 + j;
        float f = (k < 428) ? Wih[(u64)grow*428 + k] : ((k==428) ? (bih[grow]+bhh[grow]) : 0.0f);
        v[j] = (short)f2b(f);
      }
      BWih[nt][kk] = v;
    }
    #pragma unroll
    for (int kk=0; kk<10; ++kk){
      bf16x8 v;
      #pragma unroll
      for (int j=0;j<8;++j)
        v[j] = (short)f2b(Whh[(u64)grow*320 + kk*32 + 8*l4 + j]);
      BWhh[nt][kk] = v;
    }
  }

  float cst[8];
  #pragma unroll
  for (int p=0;p<8;++p) cst[p]=0.0f;

  f32x4 accA[2][4], accB[2][4];
  pre_compute(accA, dir ? 255 : 0, xg, Xs, BWih, tid, l15, l4);

  for (int ii = 0; ii < 256; ii += 2){
    int t0 = dir ? 255-ii : ii;
    word_body(ii,   dir, wg, t0, accA, accB, BWih, BWhh, cst, xg, h_g, flags, hs, Hs, Xs, G, tid, l15, l4, wv, ucol, ub0);
    int t1 = dir ? 254-ii : ii+1;
    word_body(ii+1, dir, wg, t1, accB, accA, BWih, BWhh, cst, xg, h_g, flags, hs, Hs, Xs, G, tid, l15, l4, wv, ucol, ub0);
  }
}

// ---------------- tag projection: [16384][640] @ W_tag.T + b_tag -> f32 out ----------------
__global__ __launch_bounds__(256,1) void k_tag(
    const u16* __restrict__ hs, const float* __restrict__ Wt,
    const float* __restrict__ bt, float* __restrict__ out)
{
  __shared__ __align__(16) u16 Wl[32*648];
  __shared__ float btl[32];
  const int tid = threadIdx.x;
  const int lane = tid & 63, wv = tid >> 6;
  const int l15 = lane & 15, l4 = lane >> 4;
  const int r0 = blockIdx.x * 64;

  for (int p=0; p<80; ++p){
    int idx = tid + 256*p;
    int nq = idx / 640, k = idx - nq*640;
    Wl[nq*648 + k] = (nq < 20) ? f2b(Wt[(u64)nq*640 + k]) : (u16)0;
  }
  if (tid < 32) btl[tid] = (tid < 20) ? bt[tid] : 0.0f;
  __syncthreads();

  f32x4 acc[2];
  #pragma unroll
  for (int nt=0;nt<2;++nt)
    #pragma unroll
    for (int j=0;j<4;++j) acc[nt][j]=0.0f;

  const int mrow = r0 + wv*16 + l15;
  #pragma unroll
  for (int kk=0; kk<20; ++kk){
    bf16x8 A = *(const bf16x8*)&hs[(u64)mrow*640 + kk*32 + 8*l4];
    #pragma unroll
    for (int nt=0; nt<2; ++nt){
      bf16x8 Bf = *(const bf16x8*)&Wl[(nt*16 + l15)*648 + kk*32 + 8*l4];
      acc[nt] = __builtin_amdgcn_mfma_f32_16x16x32_bf16(A, Bf, acc[nt], 0,0,0);
    }
  }
  #pragma unroll
  for (int nt=0; nt<2; ++nt){
    int nq = nt*16 + l15;
    if (nq < 20){
      #pragma unroll
      for (int j=0;j<4;++j){
        int row = r0 + wv*16 + l4*4 + j;
        out[(u64)row*20 + nq] = acc[nt][j] + btl[nq];
      }
    }
  }
}

extern "C" void kernel_launch(void* const* d_in, const int* in_sizes, int n_in,
                              void* d_out, int out_size, void* d_ws, size_t ws_size,
                              hipStream_t stream)
{
  (void)in_sizes; (void)n_in; (void)out_size; (void)ws_size;
  const int*   sents   = (const int*)d_in[0];
  const int*   charids = (const int*)d_in[2];
  const float* wemb    = (const float*)d_in[3];
  const float* cemb    = (const float*)d_in[4];
  const float* ch0     = (const float*)d_in[5];
  const float* cc0     = (const float*)d_in[6];
  const float* Wih_cf  = (const float*)d_in[7];
  const float* Whh_cf  = (const float*)d_in[8];
  const float* bih_cf  = (const float*)d_in[9];
  const float* bhh_cf  = (const float*)d_in[10];
  const float* Wih_cb  = (const float*)d_in[11];
  const float* Whh_cb  = (const float*)d_in[12];
  const float* bih_cb  = (const float*)d_in[13];
  const float* bhh_cb  = (const float*)d_in[14];
  const float* Wih_wf  = (const float*)d_in[15];
  const float* Whh_wf  = (const float*)d_in[16];
  const float* bih_wf  = (const float*)d_in[17];
  const float* bhh_wf  = (const float*)d_in[18];
  const float* Wih_wb  = (const float*)d_in[19];
  const float* Whh_wb  = (const float*)d_in[20];
  const float* bih_wb  = (const float*)d_in[21];
  const float* bhh_wb  = (const float*)d_in[22];
  const float* W_tag   = (const float*)d_in[23];
  const float* b_tag   = (const float*)d_in[24];

  // workspace layout (bytes), total ~38.2 MB
  char* ws = (char*)d_ws;
  u32* flags = (u32*)(ws);                    //      256 B
  u16* h_g   = (u16*)(ws + 256);              //  163840 B: [parity][dir][64][320] bf16
  u16* cf_f  = (u16*)(ws + 164096);           //  2.10 MB: [16384][64] bf16
  u16* cf_b  = (u16*)(ws + 2261248);          //  2.10 MB
  u16* x     = (u16*)(ws + 4358400);          // 14.68 MB: [16384][448] bf16
  u16* hs    = (u16*)(ws + 19038464);         // 20.97 MB: [16384][640] bf16
  float* outp = (float*)d_out;

  hipLaunchKernelGGL(k_init, dim3(1), dim3(64), 0, stream, flags);
  hipLaunchKernelGGL(k_char, dim3(512), dim3(256), 0, stream,
    charids, cemb, ch0, cc0, Wih_cf, Whh_cf, bih_cf, bhh_cf,
    Wih_cb, Whh_cb, bih_cb, bhh_cb, cf_f, cf_b);
  hipLaunchKernelGGL(k_buildx, dim3(4096), dim3(256), 0, stream, sents, wemb, cf_f, cf_b, x);
  hipLaunchKernelGGL(k_word, dim3(20), dim3(256), 0, stream,
    x, Wih_wf, Whh_wf, bih_wf, bhh_wf, Wih_wb, Whh_wb, bih_wb, bhh_wb, h_g, flags, hs);
  hipLaunchKernelGGL(k_tag, dim3(256), dim3(256), 0, stream, hs, W_tag, b_tag, outp);
}

// Round 2
// 2548.354 us; speedup vs baseline: 2.4029x; 2.4029x over previous
//
#include <hip/hip_runtime.h>
#include <stdint.h>

typedef __attribute__((ext_vector_type(8))) short bf16x8;
typedef __attribute__((ext_vector_type(4))) float f32x4;
typedef unsigned short u16;
typedef unsigned int u32;
typedef unsigned long long u64;

#define DEV static __device__ __forceinline__

// Problem constants: B=64, S=256, C=12, Ec=50, Hc=64, Ew=300, Hw=320, Din=428, NT=20
// word count N = B*S = 16384. x rows are r = t*64 + b (time-major == packed order).

DEV u16 f2b(float f){ union{float f; u32 u;} v; v.f=f; return (u16)((v.u + 0x7FFFu + ((v.u>>16)&1u))>>16); }
DEV float b2f(u16 b){ union{u32 u; float f;} v; v.u=((u32)b)<<16; return v.f; }
DEV float sigm(float x){ return 1.0f/(1.0f + __expf(-x)); }
DEV float tanhf2(float x){ float a=fabsf(x); float e=__expf(-2.0f*a); float t=(1.0f-e)/(1.0f+e); return x<0.0f? -t : t; }

// ---------------- flag init ----------------
__global__ void k_init(u32* flags){ flags[threadIdx.x] = 0u; }

// ---------------- char BiLSTM (fused emb-gather + input-proj + recurrence) ----------------
__global__ __launch_bounds__(256,1) void k_char(
    const int* __restrict__ char_ids, const float* __restrict__ cemb,
    const float* __restrict__ h0g, const float* __restrict__ c0g,
    const float* __restrict__ WihF, const float* __restrict__ WhhF,
    const float* __restrict__ bihF, const float* __restrict__ bhhF,
    const float* __restrict__ WihB, const float* __restrict__ WhhB,
    const float* __restrict__ bihB, const float* __restrict__ bhhB,
    u16* __restrict__ cfF, u16* __restrict__ cfB)
{
  __shared__ __align__(16) u16 Wl[256*128];  // swizzled [n][k]
  __shared__ __align__(16) u16 Xc[64*128];   // swizzled [word][k] = [emb(50)|h(64)|1|0pad]
  __shared__ __align__(16) u16 Gc[64*256];   // gates bf16

  const int dir = blockIdx.x & 1;
  const int n0  = (blockIdx.x >> 1) * 64;
  const int tid = threadIdx.x;
  const int lane = tid & 63, wv = tid >> 6;
  const int l15 = lane & 15, l4 = lane >> 4;

  const float* Wih = dir ? WihB : WihF;
  const float* Whh = dir ? WhhB : WhhF;
  const float* bih = dir ? bihB : bihF;
  const float* bhh = dir ? bhhB : bhhF;
  const float* h0 = h0g + dir*64;
  const float* c0 = c0g + dir*64;

  {
    const int n = tid; const int gt = n & 3, col = n >> 2;
    const int grow = gt*64 + col;
    for (int k = 0; k < 128; ++k){
      float v;
      if (k < 50) v = Wih[grow*50 + k];
      else if (k < 114) v = Whh[grow*64 + (k-50)];
      else if (k == 114) v = bih[grow] + bhh[grow];
      else v = 0.0f;
      Wl[n*128 + (k ^ ((n&7)<<3))] = f2b(v);
    }
  }
  for (int idx = tid; idx < 64*128; idx += 256){
    int w = idx >> 7, k = idx & 127;
    float v = (k==114) ? 1.0f : ((k>=50 && k<114) ? h0[k-50] : 0.0f);
    Xc[w*128 + (k ^ ((w&7)<<3))] = f2b(v);
  }
  const int uw = tid >> 2, ucb = (tid & 3) * 16;
  float cst[16], hreg[16];
  #pragma unroll
  for (int cc = 0; cc < 16; ++cc){ cst[cc] = c0[ucb + cc]; hreg[cc] = 0.0f; }

  for (int t = 0; t < 12; ++t){
    const int cpos = dir ? (11 - t) : t;
    __syncthreads();
    for (int idx = tid; idx < 3200; idx += 256){
      int w = idx / 50, k = idx - w*50;
      int cid = char_ids[(n0 + w)*12 + cpos];
      Xc[w*128 + (k ^ ((w&7)<<3))] = f2b(cemb[cid*50 + k]);
    }
    __syncthreads();
    f32x4 acc[4][4];
    #pragma unroll
    for (int mt=0; mt<4; ++mt)
      #pragma unroll
      for (int nt=0; nt<4; ++nt)
        #pragma unroll
        for (int j=0;j<4;++j) acc[mt][nt][j] = 0.0f;
    #pragma unroll
    for (int kk = 0; kk < 4; ++kk){
      bf16x8 A[4];
      #pragma unroll
      for (int mt=0; mt<4; ++mt){
        int row = mt*16 + l15;
        A[mt] = *(const bf16x8*)&Xc[row*128 + ((kk*32 + 8*l4) ^ ((row&7)<<3))];
      }
      #pragma unroll
      for (int nt=0; nt<4; ++nt){
        int n = wv*64 + nt*16 + l15;
        bf16x8 Bf = *(const bf16x8*)&Wl[n*128 + ((kk*32 + 8*l4) ^ ((n&7)<<3))];
        #pragma unroll
        for (int mt=0; mt<4; ++mt)
          acc[mt][nt] = __builtin_amdgcn_mfma_f32_16x16x32_bf16(A[mt], Bf, acc[mt][nt], 0,0,0);
      }
    }
    #pragma unroll
    for (int mt=0; mt<4; ++mt)
      #pragma unroll
      for (int nt=0; nt<4; ++nt)
        #pragma unroll
        for (int j=0;j<4;++j){
          int m = mt*16 + l4*4 + j;
          int n = wv*64 + nt*16 + l15;
          Gc[m*256 + n] = f2b(acc[mt][nt][j]);
        }
    __syncthreads();
    #pragma unroll
    for (int cc=0; cc<16; ++cc){
      int col = ucb + cc;
      const u16* gp = &Gc[uw*256 + col*4];
      float gi=b2f(gp[0]), gf=b2f(gp[1]), gg=b2f(gp[2]), go=b2f(gp[3]);
      float c2 = sigm(gf)*cst[cc] + sigm(gi)*tanhf2(gg);
      cst[cc]=c2;
      float h = sigm(go)*tanhf2(c2);
      hreg[cc]=h;
      Xc[uw*128 + ((50+col) ^ ((uw&7)<<3))] = f2b(h);
    }
  }
  u16* cf = dir ? cfB : cfF;
  #pragma unroll
  for (int cc=0; cc<16; ++cc) cf[(u64)(n0+uw)*64 + ucb + cc] = f2b(hreg[cc]);
}

// ---------------- build x [16384][448] bf16: [we(300)|cf_f(64)|cf_b(64)|1|0..] ----------------
__global__ __launch_bounds__(256,1) void k_buildx(
    const int* __restrict__ sents, const float* __restrict__ wemb,
    const u16* __restrict__ cfF, const u16* __restrict__ cfB,
    u16* __restrict__ xg)
{
  const int r = blockIdx.x*4 + (threadIdx.x >> 6);
  const int lane = threadIdx.x & 63;
  const int t = r >> 6, b = r & 63;
  const int sid = sents[b*256 + t];
  const int n = b*256 + t;                    // char word index (b-major)
  u32* xr = (u32*)(xg + (u64)r*448);
  const float* we = wemb + (u64)sid*300;
  const u16* cf = cfF + (u64)n*64;
  const u16* cb = cfB + (u64)n*64;
  for (int u = lane; u < 224; u += 64){
    int c0 = 2*u, c1 = 2*u + 1;
    u16 lo = (c0 < 300) ? f2b(we[c0]) : (c0 < 364) ? cf[c0-300] : (c0 < 428) ? cb[c0-364] : (c0==428) ? f2b(1.0f) : (u16)0;
    u16 hi = (c1 < 300) ? f2b(we[c1]) : (c1 < 364) ? cf[c1-300] : (c1 < 428) ? cb[c1-364] : (c1==428) ? f2b(1.0f) : (u16)0;
    xr[u] = (u32)lo | ((u32)hi << 16);
  }
}

// ---------------- word BiLSTM: 2 XCD-clustered groups of 10 WGs (32 h-cols each) ----------------
// All inter-WG traffic stays inside one XCD's L2: plain write-through stores +
// sc0 (L1-bypass) flag loads + buffer_inv (vector-L1-only). NO agent-scope
// coherence ops (buffer_wbl2/inv sc1) anywhere in the loop.

DEV void pre_compute(f32x4 (&ACC)[2][4], int tn,
                     const u16* __restrict__ xg, u16* Xs,
                     const bf16x8 (&BWih)[2][14],
                     int tid, int l15, int l4)
{
  {
    const u16* src = xg + (u64)tn * 64 * 448;
    #pragma unroll
    for (int p = 0; p < 14; ++p){
      int idx = tid + 256*p;
      int row = idx / 56, e = idx - row*56;      // 56 x 16B units per 448-col row
      f32x4 v = *(const f32x4*)(src + row*448 + e*8);
      *(f32x4*)&Xs[row*456 + e*8] = v;
    }
  }
  __syncthreads();
  #pragma unroll
  for (int nt=0; nt<2; ++nt)
    #pragma unroll
    for (int mt=0; mt<4; ++mt)
      #pragma unroll
      for (int j=0;j<4;++j) ACC[nt][mt][j] = 0.0f;
  #pragma unroll
  for (int kk = 0; kk < 14; ++kk){
    bf16x8 A[4];
    #pragma unroll
    for (int mt=0; mt<4; ++mt)
      A[mt] = *(const bf16x8*)&Xs[(mt*16 + l15)*456 + kk*32 + 8*l4];
    #pragma unroll
    for (int nt=0; nt<2; ++nt)
      #pragma unroll
      for (int mt=0; mt<4; ++mt)
        ACC[nt][mt] = __builtin_amdgcn_mfma_f32_16x16x32_bf16(A[mt], BWih[nt][kk], ACC[nt][mt], 0,0,0);
  }
}

DEV void word_body(int i, int dir, int wg, int t,
                   f32x4 (&ACCC)[2][4], f32x4 (&ACCN)[2][4],
                   const bf16x8 (&BWih)[2][14], const bf16x8 (&BWhh)[2][10],
                   float (&cst)[8],
                   const u16* __restrict__ xg, u16* __restrict__ h_g,
                   u32* __restrict__ flags, u16* __restrict__ hs,
                   u16* Hs, u16* Xs, float* G,
                   int tid, int l15, int l4, int wv, int ucol, int ub0)
{
  if (i > 0){
    if (tid < 10){
      const u32 tgt = (u32)i;
      const u32* fp = &flags[dir*16 + tid];
      int guard = 0;
      for (;;){
        u32 v;
        asm volatile("global_load_dword %0, %1, off sc0\n\ts_waitcnt vmcnt(0)"
                     : "=v"(v) : "v"(fp) : "memory");
        if (v >= tgt) break;
        __builtin_amdgcn_s_sleep(1);
        if (++guard > (1<<19)) break;   // safety: never triggers when protocol healthy
      }
    }
    __syncthreads();
    asm volatile("buffer_inv" ::: "memory");   // drop stale vector-L1 lines (per-CU, cheap)
    {
      const u16* hb = h_g + (u64)(((i-1)&1)*2 + dir)*64*320;
      #pragma unroll
      for (int p=0; p<10; ++p){
        int idx = tid + 256*p;
        int row = idx / 40, e = idx - row*40;   // 40 x 16B units per 320-col row
        f32x4 v = *(const f32x4*)(hb + row*320 + e*8);
        *(f32x4*)&Hs[row*328 + e*8] = v;
      }
    }
    __syncthreads();
    #pragma unroll
    for (int kk=0; kk<10; ++kk){
      bf16x8 A[4];
      #pragma unroll
      for (int mt=0; mt<4; ++mt)
        A[mt] = *(const bf16x8*)&Hs[(mt*16 + l15)*328 + kk*32 + 8*l4];
      #pragma unroll
      for (int nt=0; nt<2; ++nt)
        #pragma unroll
        for (int mt=0; mt<4; ++mt)
          ACCC[nt][mt] = __builtin_amdgcn_mfma_f32_16x16x32_bf16(A[mt], BWhh[nt][kk], ACCC[nt][mt], 0,0,0);
    }
  }
  #pragma unroll
  for (int nt=0; nt<2; ++nt)
    #pragma unroll
    for (int mt=0; mt<4; ++mt)
      #pragma unroll
      for (int j=0;j<4;++j)
        G[(mt*16 + l4*4 + j)*128 + wv*32 + nt*16 + l15] = ACCC[nt][mt][j];
  __syncthreads();
  {
    u16* hw = h_g + (u64)((i&1)*2 + dir)*64*320;
    #pragma unroll
    for (int p=0; p<8; ++p){
      int b = ub0 + 8*p;
      const float4 g4 = *(const float4*)&G[b*128 + ucol*4];   // (i,f,g,o)
      float c2 = sigm(g4.y)*cst[p] + sigm(g4.x)*tanhf2(g4.z);
      cst[p] = c2;
      float h = sigm(g4.w)*tanhf2(c2);
      u16 hb16 = f2b(h);
      hw[b*320 + wg*32 + ucol] = hb16;                       // write-through -> same-XCD L2
      hs[(u64)(t*64 + b)*640 + dir*320 + wg*32 + ucol] = hb16;
    }
  }
  __syncthreads();   // compiler emits s_waitcnt vmcnt(0) before s_barrier: all h stores in L2
  if (tid == 0){
    u32 nv = (u32)(i+1);
    asm volatile("s_waitcnt vmcnt(0)\n\tglobal_store_dword %0, %1, off sc0"
                 :: "v"(&flags[dir*16 + wg]), "v"(nv) : "memory");
  }
  if (i < 255){
    int tn = dir ? (254 - i) : (i + 1);
    pre_compute(ACCN, tn, xg, Xs, BWih, tid, l15, l4);   // fills the spin slack of other WGs
  }
}

__global__ __launch_bounds__(256,1) void k_word(
    const u16* __restrict__ xg,
    const float* __restrict__ WihFg, const float* __restrict__ WhhFg,
    const float* __restrict__ bihFg, const float* __restrict__ bhhFg,
    const float* __restrict__ WihBg, const float* __restrict__ WhhBg,
    const float* __restrict__ bihBg, const float* __restrict__ bhhBg,
    u16* __restrict__ h_g, u32* __restrict__ flags, u16* __restrict__ hs)
{
  __shared__ __align__(16) u16 Hs[64*328];   // h stage, padded stride
  __shared__ __align__(16) u16 Xs[64*456];   // x slice stage, padded stride
  __shared__ __align__(16) float G[64*128];  // gate redistribute
  __shared__ int s_dir, s_wg;

  // --- XCD-clustered claim: fwd = first 10 WGs on XCD0, bwd = first 10 on XCD1 ---
  if (threadIdx.x == 0){
    u32 xcd;
    asm("s_getreg_b32 %0, hwreg(HW_REG_XCC_ID)" : "=s"(xcd));
    xcd &= 7u;
    int dir = -1, wg = 0;
    if (xcd <= 1u){
      u32 slot = atomicAdd(&flags[32 + xcd], 1u);
      if (slot < 10u){ dir = (int)xcd; wg = (int)slot; }
    }
    s_dir = dir; s_wg = wg;
  }
  __syncthreads();
  const int dir = s_dir, wg = s_wg;
  if (dir < 0) return;

  const int tid = threadIdx.x;
  const int lane = tid & 63, wv = tid >> 6;
  const int l15 = lane & 15, l4 = lane >> 4;
  const int ucol = tid & 31, ub0 = tid >> 5;

  const float* Wih = dir ? WihBg : WihFg;
  const float* Whh = dir ? WhhBg : WhhFg;
  const float* bih = dir ? bihBg : bihFg;
  const float* bhh = dir ? bhhBg : bhhFg;

  // persistent weight fragments in registers. local gate q = col*4 + gtype.
  bf16x8 BWih[2][14];
  bf16x8 BWhh[2][10];
  #pragma unroll
  for (int nt=0; nt<2; ++nt){
    const int q = wv*32 + nt*16 + l15;
    const int col = q >> 2, gt = q & 3;
    const int grow = gt*320 + wg*32 + col;
    #pragma unroll
    for (int kk=0; kk<14; ++kk){
      bf16x8 v;
      #pragma unroll
      for (int j=0;j<8;++j){
        int k = kk*32 + 8*l4 + j;
        float f = (k < 428) ? Wih[(u64)grow*428 + k] : ((k==428) ? (bih[grow]+bhh[grow]) : 0.0f);
        v[j] = (short)f2b(f);
      }
      BWih[nt][kk] = v;
    }
    #pragma unroll
    for (int kk=0; kk<10; ++kk){
      bf16x8 v;
      #pragma unroll
      for (int j=0;j<8;++j)
        v[j] = (short)f2b(Whh[(u64)grow*320 + kk*32 + 8*l4 + j]);
      BWhh[nt][kk] = v;
    }
  }

  float cst[8];
  #pragma unroll
  for (int p=0;p<8;++p) cst[p]=0.0f;

  f32x4 accA[2][4], accB[2][4];
  pre_compute(accA, dir ? 255 : 0, xg, Xs, BWih, tid, l15, l4);

  for (int ii = 0; ii < 256; ii += 2){
    int t0 = dir ? 255-ii : ii;
    word_body(ii,   dir, wg, t0, accA, accB, BWih, BWhh, cst, xg, h_g, flags, hs, Hs, Xs, G, tid, l15, l4, wv, ucol, ub0);
    int t1 = dir ? 254-ii : ii+1;
    word_body(ii+1, dir, wg, t1, accB, accA, BWih, BWhh, cst, xg, h_g, flags, hs, Hs, Xs, G, tid, l15, l4, wv, ucol, ub0);
  }
}

// ---------------- tag projection: [16384][640] @ W_tag.T + b_tag -> f32 out ----------------
__global__ __launch_bounds__(256,1) void k_tag(
    const u16* __restrict__ hs, const float* __restrict__ Wt,
    const float* __restrict__ bt, float* __restrict__ out)
{
  __shared__ __align__(16) u16 Wl[32*648];
  __shared__ float btl[32];
  const int tid = threadIdx.x;
  const int lane = tid & 63, wv = tid >> 6;
  const int l15 = lane & 15, l4 = lane >> 4;
  const int r0 = blockIdx.x * 64;

  for (int p=0; p<80; ++p){
    int idx = tid + 256*p;
    int nq = idx / 640, k = idx - nq*640;
    Wl[nq*648 + k] = (nq < 20) ? f2b(Wt[(u64)nq*640 + k]) : (u16)0;
  }
  if (tid < 32) btl[tid] = (tid < 20) ? bt[tid] : 0.0f;
  __syncthreads();

  f32x4 acc[2];
  #pragma unroll
  for (int nt=0;nt<2;++nt)
    #pragma unroll
    for (int j=0;j<4;++j) acc[nt][j]=0.0f;

  const int mrow = r0 + wv*16 + l15;
  #pragma unroll
  for (int kk=0; kk<20; ++kk){
    bf16x8 A = *(const bf16x8*)&hs[(u64)mrow*640 + kk*32 + 8*l4];
    #pragma unroll
    for (int nt=0; nt<2; ++nt){
      bf16x8 Bf = *(const bf16x8*)&Wl[(nt*16 + l15)*648 + kk*32 + 8*l4];
      acc[nt] = __builtin_amdgcn_mfma_f32_16x16x32_bf16(A, Bf, acc[nt], 0,0,0);
    }
  }
  #pragma unroll
  for (int nt=0; nt<2; ++nt){
    int nq = nt*16 + l15;
    if (nq < 20){
      #pragma unroll
      for (int j=0;j<4;++j){
        int row = r0 + wv*16 + l4*4 + j;
        out[(u64)row*20 + nq] = acc[nt][j] + btl[nq];
      }
    }
  }
}

extern "C" void kernel_launch(void* const* d_in, const int* in_sizes, int n_in,
                              void* d_out, int out_size, void* d_ws, size_t ws_size,
                              hipStream_t stream)
{
  (void)in_sizes; (void)n_in; (void)out_size; (void)ws_size;
  const int*   sents   = (const int*)d_in[0];
  const int*   charids = (const int*)d_in[2];
  const float* wemb    = (const float*)d_in[3];
  const float* cemb    = (const float*)d_in[4];
  const float* ch0     = (const float*)d_in[5];
  const float* cc0     = (const float*)d_in[6];
  const float* Wih_cf  = (const float*)d_in[7];
  const float* Whh_cf  = (const float*)d_in[8];
  const float* bih_cf  = (const float*)d_in[9];
  const float* bhh_cf  = (const float*)d_in[10];
  const float* Wih_cb  = (const float*)d_in[11];
  const float* Whh_cb  = (const float*)d_in[12];
  const float* bih_cb  = (const float*)d_in[13];
  const float* bhh_cb  = (const float*)d_in[14];
  const float* Wih_wf  = (const float*)d_in[15];
  const float* Whh_wf  = (const float*)d_in[16];
  const float* bih_wf  = (const float*)d_in[17];
  const float* bhh_wf  = (const float*)d_in[18];
  const float* Wih_wb  = (const float*)d_in[19];
  const float* Whh_wb  = (const float*)d_in[20];
  const float* bih_wb  = (const float*)d_in[21];
  const float* bhh_wb  = (const float*)d_in[22];
  const float* W_tag   = (const float*)d_in[23];
  const float* b_tag   = (const float*)d_in[24];

  // workspace layout (bytes), total ~38.2 MB
  char* ws = (char*)d_ws;
  u32* flags = (u32*)(ws);                    //      256 B: [0..31] step flags, [32..39] XCD claim
  u16* h_g   = (u16*)(ws + 256);              //  163840 B: [parity][dir][64][320] bf16
  u16* cf_f  = (u16*)(ws + 164096);           //  2.10 MB: [16384][64] bf16
  u16* cf_b  = (u16*)(ws + 2261248);           //  2.10 MB
  u16* x     = (u16*)(ws + 4358400);          // 14.68 MB: [16384][448] bf16
  u16* hs    = (u16*)(ws + 19038464);         // 20.97 MB: [16384][640] bf16
  float* outp = (float*)d_out;

  hipLaunchKernelGGL(k_init, dim3(1), dim3(64), 0, stream, flags);
  hipLaunchKernelGGL(k_char, dim3(512), dim3(256), 0, stream,
    charids, cemb, ch0, cc0, Wih_cf, Whh_cf, bih_cf, bhh_cf,
    Wih_cb, Whh_cb, bih_cb, bhh_cb, cf_f, cf_b);
  hipLaunchKernelGGL(k_buildx, dim3(4096), dim3(256), 0, stream, sents, wemb, cf_f, cf_b, x);
  hipLaunchKernelGGL(k_word, dim3(256), dim3(256), 0, stream,
    x, Wih_wf, Whh_wf, bih_wf, bhh_wf, Wih_wb, Whh_wb, bih_wb, bhh_wb, h_g, flags, hs);
  hipLaunchKernelGGL(k_tag, dim3(256), dim3(256), 0, stream, hs, W_tag, b_tag, outp);
}

// Round 4
// 2161.799 us; speedup vs baseline: 2.8325x; 1.1788x over previous
//
#include <hip/hip_runtime.h>
#include <stdint.h>

typedef __attribute__((ext_vector_type(8))) short bf16x8;
typedef __attribute__((ext_vector_type(4))) float f32x4;
typedef unsigned short u16;
typedef unsigned int u32;
typedef unsigned long long u64;

#define DEV static __device__ __forceinline__

// Problem constants: B=64, S=256, C=12, Ec=50, Hc=64, Ew=300, Hw=320, Din=428, NT=20
// word count N = B*S = 16384. x rows are r = t*64 + b (time-major == packed order).

DEV u16 f2b(float f){ union{float f; u32 u;} v; v.f=f; return (u16)((v.u + 0x7FFFu + ((v.u>>16)&1u))>>16); }
DEV float b2f(u16 b){ union{u32 u; float f;} v; v.u=((u32)b)<<16; return v.f; }
DEV float sigm(float x){ return 1.0f/(1.0f + __expf(-x)); }
DEV float tanhf2(float x){ float a=fabsf(x); float e=__expf(-2.0f*a); float t=(1.0f-e)/(1.0f+e); return x<0.0f? -t : t; }

// ---------------- flag init ----------------
__global__ void k_init(u32* flags){ flags[threadIdx.x] = 0u; }

// ---------------- char BiLSTM (fused emb-gather + input-proj + recurrence) ----------------
__global__ __launch_bounds__(256,1) void k_char(
    const int* __restrict__ char_ids, const float* __restrict__ cemb,
    const float* __restrict__ h0g, const float* __restrict__ c0g,
    const float* __restrict__ WihF, const float* __restrict__ WhhF,
    const float* __restrict__ bihF, const float* __restrict__ bhhF,
    const float* __restrict__ WihB, const float* __restrict__ WhhB,
    const float* __restrict__ bihB, const float* __restrict__ bhhB,
    u16* __restrict__ cfF, u16* __restrict__ cfB)
{
  __shared__ __align__(16) u16 Wl[256*128];  // swizzled [n][k]
  __shared__ __align__(16) u16 Xc[64*128];   // swizzled [word][k] = [emb(50)|h(64)|1|0pad]
  __shared__ __align__(16) u16 Gc[64*256];   // gates bf16

  const int dir = blockIdx.x & 1;
  const int n0  = (blockIdx.x >> 1) * 64;
  const int tid = threadIdx.x;
  const int lane = tid & 63, wv = tid >> 6;
  const int l15 = lane & 15, l4 = lane >> 4;

  const float* Wih = dir ? WihB : WihF;
  const float* Whh = dir ? WhhB : WhhF;
  const float* bih = dir ? bihB : bihF;
  const float* bhh = dir ? bhhB : bhhF;
  const float* h0 = h0g + dir*64;
  const float* c0 = c0g + dir*64;

  {
    const int n = tid; const int gt = n & 3, col = n >> 2;
    const int grow = gt*64 + col;
    for (int k = 0; k < 128; ++k){
      float v;
      if (k < 50) v = Wih[grow*50 + k];
      else if (k < 114) v = Whh[grow*64 + (k-50)];
      else if (k == 114) v = bih[grow] + bhh[grow];
      else v = 0.0f;
      Wl[n*128 + (k ^ ((n&7)<<3))] = f2b(v);
    }
  }
  for (int idx = tid; idx < 64*128; idx += 256){
    int w = idx >> 7, k = idx & 127;
    float v = (k==114) ? 1.0f : ((k>=50 && k<114) ? h0[k-50] : 0.0f);
    Xc[w*128 + (k ^ ((w&7)<<3))] = f2b(v);
  }
  const int uw = tid >> 2, ucb = (tid & 3) * 16;
  float cst[16], hreg[16];
  #pragma unroll
  for (int cc = 0; cc < 16; ++cc){ cst[cc] = c0[ucb + cc]; hreg[cc] = 0.0f; }

  for (int t = 0; t < 12; ++t){
    const int cpos = dir ? (11 - t) : t;
    __syncthreads();
    for (int idx = tid; idx < 3200; idx += 256){
      int w = idx / 50, k = idx - w*50;
      int cid = char_ids[(n0 + w)*12 + cpos];
      Xc[w*128 + (k ^ ((w&7)<<3))] = f2b(cemb[cid*50 + k]);
    }
    __syncthreads();
    f32x4 acc[4][4];
    #pragma unroll
    for (int mt=0; mt<4; ++mt)
      #pragma unroll
      for (int nt=0; nt<4; ++nt)
        #pragma unroll
        for (int j=0;j<4;++j) acc[mt][nt][j] = 0.0f;
    #pragma unroll
    for (int kk = 0; kk < 4; ++kk){
      bf16x8 A[4];
      #pragma unroll
      for (int mt=0; mt<4; ++mt){
        int row = mt*16 + l15;
        A[mt] = *(const bf16x8*)&Xc[row*128 + ((kk*32 + 8*l4) ^ ((row&7)<<3))];
      }
      #pragma unroll
      for (int nt=0; nt<4; ++nt){
        int n = wv*64 + nt*16 + l15;
        bf16x8 Bf = *(const bf16x8*)&Wl[n*128 + ((kk*32 + 8*l4) ^ ((n&7)<<3))];
        #pragma unroll
        for (int mt=0; mt<4; ++mt)
          acc[mt][nt] = __builtin_amdgcn_mfma_f32_16x16x32_bf16(A[mt], Bf, acc[mt][nt], 0,0,0);
      }
    }
    #pragma unroll
    for (int mt=0; mt<4; ++mt)
      #pragma unroll
      for (int nt=0; nt<4; ++nt)
        #pragma unroll
        for (int j=0;j<4;++j){
          int m = mt*16 + l4*4 + j;
          int n = wv*64 + nt*16 + l15;
          Gc[m*256 + n] = f2b(acc[mt][nt][j]);
        }
    __syncthreads();
    #pragma unroll
    for (int cc=0; cc<16; ++cc){
      int col = ucb + cc;
      const u16* gp = &Gc[uw*256 + col*4];
      float gi=b2f(gp[0]), gf=b2f(gp[1]), gg=b2f(gp[2]), go=b2f(gp[3]);
      float c2 = sigm(gf)*cst[cc] + sigm(gi)*tanhf2(gg);
      cst[cc]=c2;
      float h = sigm(go)*tanhf2(c2);
      hreg[cc]=h;
      Xc[uw*128 + ((50+col) ^ ((uw&7)<<3))] = f2b(h);
    }
  }
  u16* cf = dir ? cfB : cfF;
  #pragma unroll
  for (int cc=0; cc<16; ++cc) cf[(u64)(n0+uw)*64 + ucb + cc] = f2b(hreg[cc]);
}

// ---------------- build x [16384][448] bf16: [we(300)|cf_f(64)|cf_b(64)|1|0..] ----------------
__global__ __launch_bounds__(256,1) void k_buildx(
    const int* __restrict__ sents, const float* __restrict__ wemb,
    const u16* __restrict__ cfF, const u16* __restrict__ cfB,
    u16* __restrict__ xg)
{
  const int r = blockIdx.x*4 + (threadIdx.x >> 6);
  const int lane = threadIdx.x & 63;
  const int t = r >> 6, b = r & 63;
  const int sid = sents[b*256 + t];
  const int n = b*256 + t;                    // char word index (b-major)
  u32* xr = (u32*)(xg + (u64)r*448);
  const float* we = wemb + (u64)sid*300;
  const u16* cf = cfF + (u64)n*64;
  const u16* cb = cfB + (u64)n*64;
  for (int u = lane; u < 224; u += 64){
    int c0 = 2*u, c1 = 2*u + 1;
    u16 lo = (c0 < 300) ? f2b(we[c0]) : (c0 < 364) ? cf[c0-300] : (c0 < 428) ? cb[c0-364] : (c0==428) ? f2b(1.0f) : (u16)0;
    u16 hi = (c1 < 300) ? f2b(we[c1]) : (c1 < 364) ? cf[c1-300] : (c1 < 428) ? cb[c1-364] : (c1==428) ? f2b(1.0f) : (u16)0;
    xr[u] = (u32)lo | ((u32)hi << 16);
  }
}

// ---------------- word BiLSTM: 2 XCD-clustered groups of 10 WGs (32 h-cols each) ----------------
// R2-proven protocol: sleep-throttled sc0 spin -> __syncthreads -> buffer_inv ->
// plain h loads -> MFMA -> in-reg transpose + bf16-rounded gates + EW ->
// u64-packed h stores -> all-wave vmcnt drain -> barrier -> sc0 flag publish.

DEV void stage_x(const u16* __restrict__ src, u16* Xs, int tid)
{
  #pragma unroll
  for (int half=0; half<2; ++half){
    f32x4 r[7];
    #pragma unroll
    for (int p=0;p<7;++p){ int idx=tid+256*(half*7+p); int row=idx/56, e=idx-row*56;
      r[p] = *(const f32x4*)(src + row*448 + e*8); }
    #pragma unroll
    for (int p=0;p<7;++p){ int idx=tid+256*(half*7+p); int row=idx/56, e=idx-row*56;
      *(f32x4*)&Xs[row*456 + e*8] = r[p]; }
  }
}

DEV void wih_mfma(f32x4 (&ACC)[2][4], const u16* Xs, const bf16x8 (&BWih)[2][14],
                  int l15, int l4)
{
  #pragma unroll
  for (int nt=0;nt<2;++nt)
    #pragma unroll
    for (int mt=0;mt<4;++mt)
      #pragma unroll
      for (int j=0;j<4;++j) ACC[nt][mt][j]=0.f;
  #pragma unroll
  for (int kk=0;kk<14;++kk){
    bf16x8 A[4];
    #pragma unroll
    for (int mt=0;mt<4;++mt)
      A[mt] = *(const bf16x8*)&Xs[(mt*16+l15)*456 + kk*32 + 8*l4];
    #pragma unroll
    for (int nt=0;nt<2;++nt)
      #pragma unroll
      for (int mt=0;mt<4;++mt)
        ACC[nt][mt] = __builtin_amdgcn_mfma_f32_16x16x32_bf16(A[mt], BWih[nt][kk], ACC[nt][mt],0,0,0);
  }
}

__global__ __launch_bounds__(256,1) void k_word(
    const u16* __restrict__ xg,
    const float* __restrict__ WihFg, const float* __restrict__ WhhFg,
    const float* __restrict__ bihFg, const float* __restrict__ bhhFg,
    const float* __restrict__ WihBg, const float* __restrict__ WhhBg,
    const float* __restrict__ bihBg, const float* __restrict__ bhhBg,
    u16* __restrict__ h_g, u32* __restrict__ flags, u16* __restrict__ hs)
{
  __shared__ __align__(16) u16 Hs[64*328];   // h stage, padded stride
  __shared__ __align__(16) u16 Xs[64*456];   // x slice stage, padded stride
  __shared__ int s_dir, s_wg;

  // --- XCD-clustered claim: fwd = first 10 WGs on XCD0, bwd = first 10 on XCD1 ---
  if (threadIdx.x == 0){
    u32 xcd;
    asm("s_getreg_b32 %0, hwreg(HW_REG_XCC_ID)" : "=s"(xcd));
    xcd &= 7u;
    int dir = -1, wg = 0;
    if (xcd <= 1u){
      u32 slot = atomicAdd(&flags[32 + xcd], 1u);
      if (slot < 10u){ dir = (int)xcd; wg = (int)slot; }
    }
    s_dir = dir; s_wg = wg;
  }
  __syncthreads();
  const int dir = s_dir, wg = s_wg;
  if (dir < 0) return;

  const int tid = threadIdx.x;
  const int lane = tid & 63, wv = tid >> 6;
  const int l15 = lane & 15, l4 = lane >> 4;
  const int qa = l15 & 3, qq = l15 >> 2;     // gate-lane index / col-quad index

  const float* Wih = dir ? WihBg : WihFg;
  const float* Whh = dir ? WhhBg : WhhFg;
  const float* bih = dir ? bihBg : bihFg;
  const float* bhh = dir ? bhhBg : bhhFg;

  // persistent weight fragments in registers. gate channel q = col*4 + gtype.
  bf16x8 BWih[2][14];
  bf16x8 BWhh[2][10];
  #pragma unroll
  for (int nt=0; nt<2; ++nt){
    const int q = wv*32 + nt*16 + l15;
    const int col = q >> 2, gt = q & 3;
    const int grow = gt*320 + wg*32 + col;
    #pragma unroll
    for (int kk=0; kk<14; ++kk){
      bf16x8 v;
      #pragma unroll
      for (int j=0;j<8;++j){
        int k = kk*32 + 8*l4 + j;
        float f = (k < 428) ? Wih[(u64)grow*428 + k] : ((k==428) ? (bih[grow]+bhh[grow]) : 0.0f);
        v[j] = (short)f2b(f);
      }
      BWih[nt][kk] = v;
    }
    #pragma unroll
    for (int kk=0; kk<10; ++kk){
      bf16x8 v;
      #pragma unroll
      for (int j=0;j<8;++j)
        v[j] = (short)f2b(Whh[(u64)grow*320 + kk*32 + 8*l4 + j]);
      BWhh[nt][kk] = v;
    }
  }

  float cst[8];
  #pragma unroll
  for (int p=0;p<8;++p) cst[p]=0.0f;

  f32x4 ACC[2][4];

  // prologue: stage x(t0), input projection
  stage_x(xg + (u64)(dir ? 255 : 0)*64*448, Xs, tid);
  __syncthreads();
  wih_mfma(ACC, Xs, BWih, l15, l4);

  for (int i=0; i<256; ++i){
    const int t = dir ? 255-i : i;

    if (i > 0){
      // --- C: spin for all producers' step-i flags (R2-proven form) ---
      if (tid < 10){
        const u32* fp = &flags[dir*16 + tid];
        const u32 tgt = (u32)i;
        int guard = 0;
        for (;;){
          u32 v;
          asm volatile("global_load_dword %0, %1, off sc0\n\ts_waitcnt vmcnt(0)"
                       : "=v"(v) : "v"(fp) : "memory");
          if (v >= tgt) break;
          __builtin_amdgcn_s_sleep(1);
          if (++guard > (1<<20)) break;   // safety: never triggers when protocol healthy
        }
      }
      __syncthreads();
      asm volatile("buffer_inv" ::: "memory");   // drop stale vector-L1 lines (per-CU)
      // --- D: load h(i-1), stage to LDS ---
      {
        const u16* hb = h_g + (u64)(((i-1)&1)*2 + dir)*64*320;
        #pragma unroll
        for (int p=0; p<10; ++p){
          int idx = tid + 256*p;
          int row = idx / 40, e = idx - row*40;   // 40 x 16B units per 320-col row
          f32x4 v = *(const f32x4*)(hb + row*320 + e*8);
          *(f32x4*)&Hs[row*328 + e*8] = v;
        }
      }
      __syncthreads();
      // --- F: Whh·h(i-1) accumulate ---
      #pragma unroll
      for (int kk=0; kk<10; ++kk){
        bf16x8 A[4];
        #pragma unroll
        for (int mt=0; mt<4; ++mt)
          A[mt] = *(const bf16x8*)&Hs[(mt*16 + l15)*328 + kk*32 + 8*l4];
        #pragma unroll
        for (int nt=0; nt<2; ++nt)
          #pragma unroll
          for (int mt=0; mt<4; ++mt)
            ACC[nt][mt] = __builtin_amdgcn_mfma_f32_16x16x32_bf16(A[mt], BWhh[nt][kk], ACC[nt][mt],0,0,0);
      }
    }

    // --- G: in-register 4x4 lane-quad transpose; bf16-round gates; EW; pack u64 ---
    u64 pk[2][4];   // packed 4-col h, valid in qq==0 lanes
    #pragma unroll
    for (int nt=0; nt<2; ++nt){
      #pragma unroll
      for (int mt=0; mt<4; ++mt){
        f32x4 v = ACC[nt][mt];
        // stage k=1
        float t0=__shfl_xor(v[1],1), t1=__shfl_xor(v[0],1), t2=__shfl_xor(v[3],1), t3=__shfl_xor(v[2],1);
        v[0] = (qa&1) ? t0 : v[0];
        v[1] = (qa&1) ? v[1] : t1;
        v[2] = (qa&1) ? t2 : v[2];
        v[3] = (qa&1) ? v[3] : t3;
        // stage k=2
        float u0=__shfl_xor(v[2],2), u1=__shfl_xor(v[3],2), u2=__shfl_xor(v[0],2), u3=__shfl_xor(v[1],2);
        v[0] = (qa&2) ? u0 : v[0];
        v[1] = (qa&2) ? u1 : v[1];
        v[2] = (qa&2) ? v[2] : u2;
        v[3] = (qa&2) ? v[3] : u3;
        // bf16-round gate pre-activations (matches R2's LDS round-trip numerics)
        v[0]=b2f(f2b(v[0])); v[1]=b2f(f2b(v[1])); v[2]=b2f(f2b(v[2])); v[3]=b2f(f2b(v[3]));
        // lane holds (i,f,g,o) of (b = mt*16 + l4*4 + qa, c = wv*8 + nt*4 + qq)
        const int ci = nt*4 + mt;
        float c2 = sigm(v[1])*cst[ci] + sigm(v[0])*tanhf2(v[2]);
        cst[ci] = c2;
        float h = sigm(v[3])*tanhf2(c2);
        // pack 4 cols (qq=0..3) into one u64 in the qq==0 lane
        u32 hu = (u32)f2b(h);
        u32 v01 = hu | ((u32)__shfl_xor((int)hu, 4) << 16);
        u32 v23 = (u32)__shfl_xor((int)v01, 8);
        pk[nt][mt] = (u64)v01 | ((u64)v23 << 32);
      }
    }
    // --- H: h_g u64 stores (same-XCD L2), qq==0 lanes only ---
    {
      u16* hw = h_g + (u64)((i&1)*2 + dir)*64*320;
      if (qq == 0){
        #pragma unroll
        for (int nt=0; nt<2; ++nt)
          #pragma unroll
          for (int mt=0; mt<4; ++mt){
            const int b = mt*16 + l4*4 + qa;
            *(u64*)&hw[b*320 + wg*32 + wv*8 + nt*4] = pk[nt][mt];
          }
      }
    }
    // --- I: every wave drains its OWN stores, then barrier => all h in L2 ---
    asm volatile("s_waitcnt vmcnt(0)" ::: "memory");
    __syncthreads();
    // --- J: publish flag ---
    if (tid == 0){
      u32 nv = (u32)(i+1);
      asm volatile("global_store_dword %0, %1, off sc0"
                   :: "v"(&flags[dir*16 + wg]), "v"(nv) : "memory");
    }
    // --- K: hs stores (consumed only by k_tag; off the critical path) ---
    if (qq == 0){
      #pragma unroll
      for (int nt=0; nt<2; ++nt)
        #pragma unroll
        for (int mt=0; mt<4; ++mt){
          const int b = mt*16 + l4*4 + qa;
          *(u64*)&hs[(u64)(t*64 + b)*640 + dir*320 + wg*32 + wv*8 + nt*4] = pk[nt][mt];
        }
    }
    // --- L: stage x(t+1) + input projection (overlaps other WGs' consume phase) ---
    if (i < 255){
      stage_x(xg + (u64)(dir ? 254-i : i+1)*64*448, Xs, tid);
      __syncthreads();
      wih_mfma(ACC, Xs, BWih, l15, l4);
    }
  }
}

// ---------------- tag projection: [16384][640] @ W_tag.T + b_tag -> f32 out ----------------
__global__ __launch_bounds__(256,1) void k_tag(
    const u16* __restrict__ hs, const float* __restrict__ Wt,
    const float* __restrict__ bt, float* __restrict__ out)
{
  __shared__ __align__(16) u16 Wl[32*648];
  __shared__ float btl[32];
  const int tid = threadIdx.x;
  const int lane = tid & 63, wv = tid >> 6;
  const int l15 = lane & 15, l4 = lane >> 4;
  const int r0 = blockIdx.x * 64;

  for (int p=0; p<80; ++p){
    int idx = tid + 256*p;
    int nq = idx / 640, k = idx - nq*640;
    Wl[nq*648 + k] = (nq < 20) ? f2b(Wt[(u64)nq*640 + k]) : (u16)0;
  }
  if (tid < 32) btl[tid] = (tid < 20) ? bt[tid] : 0.0f;
  __syncthreads();

  f32x4 acc[2];
  #pragma unroll
  for (int nt=0;nt<2;++nt)
    #pragma unroll
    for (int j=0;j<4;++j) acc[nt][j]=0.0f;

  const int mrow = r0 + wv*16 + l15;
  #pragma unroll
  for (int kk=0; kk<20; ++kk){
    bf16x8 A = *(const bf16x8*)&hs[(u64)mrow*640 + kk*32 + 8*l4];
    #pragma unroll
    for (int nt=0; nt<2; ++nt){
      bf16x8 Bf = *(const bf16x8*)&Wl[(nt*16 + l15)*648 + kk*32 + 8*l4];
      acc[nt] = __builtin_amdgcn_mfma_f32_16x16x32_bf16(A, Bf, acc[nt], 0,0,0);
    }
  }
  #pragma unroll
  for (int nt=0; nt<2; ++nt){
    int nq = nt*16 + l15;
    if (nq < 20){
      #pragma unroll
      for (int j=0;j<4;++j){
        int row = r0 + wv*16 + l4*4 + j;
        out[(u64)row*20 + nq] = acc[nt][j] + btl[nq];
      }
    }
  }
}

extern "C" void kernel_launch(void* const* d_in, const int* in_sizes, int n_in,
                              void* d_out, int out_size, void* d_ws, size_t ws_size,
                              hipStream_t stream)
{
  (void)in_sizes; (void)n_in; (void)out_size; (void)ws_size;
  const int*   sents   = (const int*)d_in[0];
  const int*   charids = (const int*)d_in[2];
  const float* wemb    = (const float*)d_in[3];
  const float* cemb    = (const float*)d_in[4];
  const float* ch0     = (const float*)d_in[5];
  const float* cc0     = (const float*)d_in[6];
  const float* Wih_cf  = (const float*)d_in[7];
  const float* Whh_cf  = (const float*)d_in[8];
  const float* bih_cf  = (const float*)d_in[9];
  const float* bhh_cf  = (const float*)d_in[10];
  const float* Wih_cb  = (const float*)d_in[11];
  const float* Whh_cb  = (const float*)d_in[12];
  const float* bih_cb  = (const float*)d_in[13];
  const float* bhh_cb  = (const float*)d_in[14];
  const float* Wih_wf  = (const float*)d_in[15];
  const float* Whh_wf  = (const float*)d_in[16];
  const float* bih_wf  = (const float*)d_in[17];
  const float* bhh_wf  = (const float*)d_in[18];
  const float* Wih_wb  = (const float*)d_in[19];
  const float* Whh_wb  = (const float*)d_in[20];
  const float* bih_wb  = (const float*)d_in[21];
  const float* bhh_wb  = (const float*)d_in[22];
  const float* W_tag   = (const float*)d_in[23];
  const float* b_tag   = (const float*)d_in[24];

  // workspace layout (bytes), total ~38.2 MB
  char* ws = (char*)d_ws;
  u32* flags = (u32*)(ws);                    //      256 B: [0..31] step flags, [32..39] XCD claim
  u16* h_g   = (u16*)(ws + 256);              //  163840 B: [parity][dir][64][320] bf16
  u16* cf_f  = (u16*)(ws + 164096);           //  2.10 MB: [16384][64] bf16
  u16* cf_b  = (u16*)(ws + 2261248);          //  2.10 MB
  u16* x     = (u16*)(ws + 4358400);          // 14.68 MB: [16384][448] bf16
  u16* hs    = (u16*)(ws + 19038464);         // 20.97 MB: [16384][640] bf16
  float* outp = (float*)d_out;

  hipLaunchKernelGGL(k_init, dim3(1), dim3(64), 0, stream, flags);
  hipLaunchKernelGGL(k_char, dim3(512), dim3(256), 0, stream,
    charids, cemb, ch0, cc0, Wih_cf, Whh_cf, bih_cf, bhh_cf,
    Wih_cb, Whh_cb, bih_cb, bhh_cb, cf_f, cf_b);
  hipLaunchKernelGGL(k_buildx, dim3(4096), dim3(256), 0, stream, sents, wemb, cf_f, cf_b, x);
  hipLaunchKernelGGL(k_word, dim3(256), dim3(256), 0, stream,
    x, Wih_wf, Whh_wf, bih_wf, bhh_wf, Wih_wb, Whh_wb, bih_wb, bhh_wb, h_g, flags, hs);
  hipLaunchKernelGGL(k_tag, dim3(256), dim3(256), 0, stream, hs, W_tag, b_tag, outp);
}